// Round 1
// baseline (92.179 us; speedup 1.0000x reference)
//
#include <hip/hip_runtime.h>

#define IN_CH 16
#define OUT_CH 32
#define NUM_INPUTS 144   // IN_CH * 3 * 3
#define BATCH 8
#define H_ 32
#define W_ 32
#define TILE_H 8
#define LDS_H 10         // TILE_H + 2 halo
#define LDS_W 34         // W + 2 halo; 34 mod 32 == 2 -> 2 lanes/bank (free)

// ---------------------------------------------------------------------------
// Prep: per (i,o) pair compute segment params for
//   y(p) = m0*p + b0 + (m1-m0)*max(p - pos1, 0)
// which equals the reference piecewise-linear (incl. both extrapolation
// tails, since the function is continuous at pos1 and idx is clipped to the
// end segments). Also reduce b0sum[o] = sum_i b0[i,o] so the main kernel can
// fold the constant term into the accumulator init (saves 1 VALU/eval).
// ---------------------------------------------------------------------------
__global__ void apc_prep(const float* __restrict__ pos,
                         const float* __restrict__ val,
                         float4* __restrict__ tab,
                         float* __restrict__ b0sum) {
    __shared__ float lb[OUT_CH];
    int tid = threadIdx.x;
    if (tid < OUT_CH) lb[tid] = 0.f;
    __syncthreads();
    for (int idx = tid; idx < NUM_INPUTS * OUT_CH; idx += 256) {
        const float* pp = pos + idx * 3;
        const float* vv = val + idx * 3;
        float p0 = pp[0], p1 = pp[1], p2 = pp[2];
        float v0 = vv[0], v1 = vv[1], v2 = vv[2];
        float m0 = (v1 - v0) / (p1 - p0);
        float m1 = (v2 - v1) / (p2 - p1);
        float b0 = v0 - m0 * p0;
        tab[idx] = make_float4(p1, m0, m1 - m0, 0.f);
        atomicAdd(&lb[idx & (OUT_CH - 1)], b0);   // idx = i*32 + o
    }
    __syncthreads();
    if (tid < OUT_CH) b0sum[tid] = lb[tid];
}

// ---------------------------------------------------------------------------
// Main: grid (32 spatial tiles, 16 o-groups), block 256.
// Block covers one batch image's 8x32 output rows for 2 output channels.
// x tile (16ch x 10 x 34, zero-padded halo) staged in LDS.
// Thread = (row = tid>>5, col = tid&31); wave = 2 adjacent rows -> LDS
// conflict-free (stride 34 == 2 mod 32 => exactly 2 lanes/bank).
// Table reads are wave-uniform -> scalar loads (s_load_dwordx4).
// ---------------------------------------------------------------------------
__global__ __launch_bounds__(256, 2) void apc_main(
        const float* __restrict__ x,
        const float4* __restrict__ tab,
        const float* __restrict__ b0sum,
        float* __restrict__ out) {
    __shared__ float lx[IN_CH * LDS_H * LDS_W];

    int bx  = blockIdx.x;          // 0..31: b*4 + row_tile
    int b   = bx >> 2;
    int ho0 = (bx & 3) * TILE_H;
    int tid = threadIdx.x;

    // Stage x tile with zero-padded halo.
    for (int idx = tid; idx < IN_CH * LDS_H * LDS_W; idx += 256) {
        int c   = idx / (LDS_H * LDS_W);
        int rem = idx - c * (LDS_H * LDS_W);
        int r   = rem / LDS_W;
        int col = rem - r * LDS_W;
        int gr  = ho0 + r - 1;
        int gc  = col - 1;
        float v = 0.f;
        if ((unsigned)gr < (unsigned)H_ && (unsigned)gc < (unsigned)W_)
            v = x[((b * IN_CH + c) * H_ + gr) * W_ + gc];
        lx[idx] = v;
    }
    __syncthreads();

    int rl    = tid >> 5;          // 0..7 local output row
    int col   = tid & 31;          // output col
    int baseA = rl * LDS_W + col;
    int o0    = blockIdx.y * 2;    // 2 output channels per block

    float a0 = b0sum[o0],     h0 = 0.f;   // split chains: Σ m0*p  and  Σ dm*relu
    float a1 = b0sum[o0 + 1], h1 = 0.f;

    #pragma unroll
    for (int c = 0; c < IN_CH; ++c) {
        #pragma unroll
        for (int kh = 0; kh < 3; ++kh) {
            #pragma unroll
            for (int kw = 0; kw < 3; ++kw) {
                int i = (c * 3 + kh) * 3 + kw;          // (c, kh, kw) ordering
                float p = lx[c * (LDS_H * LDS_W) + kh * LDS_W + kw + baseA];
                float4 t0 = tab[i * OUT_CH + o0];
                float4 t1 = tab[i * OUT_CH + o0 + 1];
                a0 = fmaf(t0.y, p, a0);
                h0 = fmaf(t0.z, fmaxf(p - t0.x, 0.f), h0);
                a1 = fmaf(t1.y, p, a1);
                h1 = fmaf(t1.z, fmaxf(p - t1.x, 0.f), h1);
            }
        }
    }

    int ho = ho0 + rl;
    out[((b * OUT_CH + o0    ) * H_ + ho) * W_ + col] = a0 + h0;
    out[((b * OUT_CH + o0 + 1) * H_ + ho) * W_ + col] = a1 + h1;
}

extern "C" void kernel_launch(void* const* d_in, const int* in_sizes, int n_in,
                              void* d_out, int out_size, void* d_ws, size_t ws_size,
                              hipStream_t stream) {
    const float* x   = (const float*)d_in[0];
    const float* pos = (const float*)d_in[1];
    const float* val = (const float*)d_in[2];

    float4* tab   = (float4*)d_ws;                                   // 73728 B
    float* b0sum  = (float*)((char*)d_ws + NUM_INPUTS * OUT_CH * sizeof(float4));

    apc_prep<<<1, 256, 0, stream>>>(pos, val, tab, b0sum);

    dim3 grid(32, 16);
    apc_main<<<grid, 256, 0, stream>>>(x, tab, b0sum, (float*)d_out);
}